// Round 3
// baseline (139.945 us; speedup 1.0000x reference)
//
#include <hip/hip_runtime.h>

#define D 32

typedef _Float16 half8 __attribute__((ext_vector_type(8)));

// ---------------------------------------------------------------------------
// Kernel 1: Y16[r][:] = fp16(X[r][:] @ W) for r < n;  Y16[n][:] = 0.
// Two rows per wave (half-wave each), float4 vector loads of the X row,
// W column held in registers (lane j holds W[:,j]).
// ---------------------------------------------------------------------------
__global__ __launch_bounds__(256, 8)
void xw_kernel(const float* __restrict__ X, const float* __restrict__ W,
               _Float16* __restrict__ Y16, int n) {
    const int lane = threadIdx.x & 63;
    const int j    = lane & 31;     // output feature
    const int h    = lane >> 5;     // which row of the pair
    const int wid  = (blockIdx.x * blockDim.x + threadIdx.x) >> 6;
    const int nw   = (gridDim.x * blockDim.x) >> 6;

    float w[D];
    #pragma unroll
    for (int d = 0; d < D; ++d) w[d] = W[d * D + j];

    for (int r0 = 2 * wid; r0 <= n; r0 += 2 * nw) {
        const int r = r0 + h;
        float o = 0.f;
        if (r < n) {
            const float4* xr = (const float4*)(X + (size_t)r * D);
            #pragma unroll
            for (int k = 0; k < 8; ++k) {
                float4 xv = xr[k];
                o = fmaf(xv.x, w[4 * k    ], o);
                o = fmaf(xv.y, w[4 * k + 1], o);
                o = fmaf(xv.z, w[4 * k + 2], o);
                o = fmaf(xv.w, w[4 * k + 3], o);
            }
        }
        if (r <= n) Y16[(size_t)r * D + j] = (_Float16)o;  // row n -> zeros
    }
}

// ---------------------------------------------------------------------------
// Kernel 2: out[r][:] = sum_{e in row r} Y16[ci[e]][:]  (f32 accumulation)
// 16 edges x 4 half8-slots per gather instruction; invalid slots gather the
// zero row Y16[n]. Persistent waves with 1-deep cross-row ci/rp prefetch.
// ---------------------------------------------------------------------------
template <int K>
__device__ __forceinline__ void gather16(const _Float16* __restrict__ Y16,
                                         int myci, int base, int g, int s,
                                         float* acc) {
    half8 x[K];
    #pragma unroll
    for (int it = 0; it < K; ++it) {
        int c = __shfl(myci, (base + it) * 16 + g, 64);   // zrow for invalid
        x[it] = ((const half8*)(Y16 + (size_t)(unsigned)c * D))[s];
    }
    #pragma unroll
    for (int it = 0; it < K; ++it) {
        #pragma unroll
        for (int e = 0; e < 8; ++e) acc[e] += (float)x[it][e];
    }
}

__device__ __forceinline__ void ladder16(const _Float16* __restrict__ Y16,
                                         int myci, int nv, int g, int s,
                                         float* acc) {
    switch ((nv + 15) >> 4) {           // wave-uniform, nv in [1,64]
        case 1:  gather16<1>(Y16, myci, 0, g, s, acc); break;
        case 2:  gather16<2>(Y16, myci, 0, g, s, acc); break;
        case 3:  gather16<3>(Y16, myci, 0, g, s, acc); break;
        default: gather16<4>(Y16, myci, 0, g, s, acc); break;
    }
}

__global__ __launch_bounds__(256, 8)
void agg_kernel(const _Float16* __restrict__ Y16, const int* __restrict__ rp,
                const int* __restrict__ ci, float* __restrict__ out, int n) {
    const int lane = threadIdx.x & 63;
    const int g  = lane >> 2;    // edge sub-group 0..15
    const int s  = lane & 3;     // half8 slot 0..3
    const int zr = n;            // zero row index

    const int wid = (blockIdx.x * blockDim.x + threadIdx.x) >> 6;
    const int nw  = (gridDim.x * blockDim.x) >> 6;

    int r = __builtin_amdgcn_readfirstlane(wid);
    if (r >= n) return;

    int start = rp[r];
    int end   = rp[r + 1];
    int nv0   = end - start; nv0 = nv0 > 64 ? 64 : nv0;
    int myci  = (lane < nv0) ? ci[start + lane] : zr;

    while (true) {
        const int deg = end - start;
        const int rn  = r + nw;
        const bool has_next = rn < n;

        // issue NEXT row's pointer+index loads first (latency hides here)
        int nstart = 0, nend = 0, next_ci = zr;
        if (has_next) {
            nstart = rp[rn];
            nend   = rp[rn + 1];
            int nnv = nend - nstart; nnv = nnv > 64 ? 64 : nnv;
            next_ci = (lane < nnv) ? ci[nstart + lane] : zr;
        }

        float acc[8] = {0.f, 0.f, 0.f, 0.f, 0.f, 0.f, 0.f, 0.f};
        if (deg > 0) {
            int nv = deg > 64 ? 64 : deg;
            ladder16(Y16, myci, nv, g, s, acc);
            for (int cb = 64; cb < deg; cb += 64) {     // rare tail (~8%)
                int rem = deg - cb;
                int nv2 = rem > 64 ? 64 : rem;
                int c2  = (lane < nv2) ? ci[start + cb + lane] : zr;
                ladder16(Y16, c2, nv2, g, s, acc);
            }
        }

        // reduce across the 16 edge groups (xor over g bits: 4,8,16,32)
        #pragma unroll
        for (int off = 4; off < 64; off <<= 1) {
            #pragma unroll
            for (int e = 0; e < 8; ++e) acc[e] += __shfl_xor(acc[e], off, 64);
        }
        // lanes 0..3 hold the row: slot s -> out[r][8s .. 8s+7]
        if (lane < 4) {
            float4* op = (float4*)(out + (size_t)r * D + s * 8);
            op[0] = make_float4(acc[0], acc[1], acc[2], acc[3]);
            op[1] = make_float4(acc[4], acc[5], acc[6], acc[7]);
        }

        if (!has_next) break;
        r = rn; start = nstart; end = nend; myci = next_ci;
    }
}

// ---------------------------------------------------------------------------
// Legacy fused kernel (fallback if workspace is too small for Y16)
// ---------------------------------------------------------------------------
__global__ __launch_bounds__(256, 4)
void gin_fused(const float* __restrict__ X,
               const float* __restrict__ W,
               const int* __restrict__ rp,
               const int* __restrict__ ci,
               float* __restrict__ out,
               int n) {
    __shared__ float Wl[D * D];

    int tid = threadIdx.x;
    {
        const float4* Wv = (const float4*)W;
        float4* Wlv = (float4*)Wl;
        Wlv[tid] = Wv[tid];
    }
    __syncthreads();

    int wave = tid >> 6;
    int lane = tid & 63;
    int row = blockIdx.x * 4 + wave;
    if (row >= n) return;

    int start = rp[row];
    int deg   = rp[row + 1] - start;

    int g = lane >> 3;
    int s = lane & 7;

    float4 acc = make_float4(0.f, 0.f, 0.f, 0.f);

    for (int cb = 0; cb < deg; cb += 64) {
        int rem = deg - cb;
        int nv  = rem < 64 ? rem : 64;
        int myci = (lane < nv) ? ci[start + cb + lane] : 0;
        {
            float4 x[4]; float m[4];
            #pragma unroll
            for (int it = 0; it < 4; ++it) {
                int l = it * 8 + g;
                int c = __shfl(myci, l, 64);
                m[it] = (l < rem) ? 1.f : 0.f;
                x[it] = ((const float4*)(X + (size_t)c * D))[s];
            }
            #pragma unroll
            for (int it = 0; it < 4; ++it) {
                acc.x = fmaf(m[it], x[it].x, acc.x);
                acc.y = fmaf(m[it], x[it].y, acc.y);
                acc.z = fmaf(m[it], x[it].z, acc.z);
                acc.w = fmaf(m[it], x[it].w, acc.w);
            }
        }
        if (rem > 32) {
            float4 x[4]; float m[4];
            #pragma unroll
            for (int it = 0; it < 4; ++it) {
                int l = (it + 4) * 8 + g;
                int c = __shfl(myci, l, 64);
                m[it] = (l < rem) ? 1.f : 0.f;
                x[it] = ((const float4*)(X + (size_t)c * D))[s];
            }
            #pragma unroll
            for (int it = 0; it < 4; ++it) {
                acc.x = fmaf(m[it], x[it].x, acc.x);
                acc.y = fmaf(m[it], x[it].y, acc.y);
                acc.z = fmaf(m[it], x[it].z, acc.z);
                acc.w = fmaf(m[it], x[it].w, acc.w);
            }
        }
    }

    #pragma unroll
    for (int off = 8; off < 64; off <<= 1) {
        acc.x += __shfl_xor(acc.x, off, 64);
        acc.y += __shfl_xor(acc.y, off, 64);
        acc.z += __shfl_xor(acc.z, off, 64);
        acc.w += __shfl_xor(acc.w, off, 64);
    }

    int j = lane & 31;
    float o = 0.f;
    #pragma unroll
    for (int sg = 0; sg < 8; ++sg) {
        float ax = __shfl(acc.x, sg, 64);
        float ay = __shfl(acc.y, sg, 64);
        float az = __shfl(acc.z, sg, 64);
        float aw = __shfl(acc.w, sg, 64);
        int d = 4 * sg;
        o = fmaf(ax, Wl[(d    ) * D + j], o);
        o = fmaf(ay, Wl[(d + 1) * D + j], o);
        o = fmaf(az, Wl[(d + 2) * D + j], o);
        o = fmaf(aw, Wl[(d + 3) * D + j], o);
    }
    if (lane < 32) out[(size_t)row * D + j] = o;
}

extern "C" void kernel_launch(void* const* d_in, const int* in_sizes, int n_in,
                              void* d_out, int out_size, void* d_ws, size_t ws_size,
                              hipStream_t stream) {
    const float* X  = (const float*)d_in[0];
    const float* W  = (const float*)d_in[1];
    const int*   rp = (const int*)d_in[2];
    const int*   ci = (const int*)d_in[3];
    float* out = (float*)d_out;

    int n = in_sizes[2] - 1;                          // N nodes
    size_t ybytes = (size_t)(n + 1) * D * sizeof(_Float16);

    if (ws_size >= ybytes) {
        _Float16* Y16 = (_Float16*)d_ws;
        hipLaunchKernelGGL(xw_kernel, dim3(2048), dim3(256), 0, stream,
                           X, W, Y16, n);
        int nwaves = (n + 3) / 4;
        int blocks = nwaves < 2048 ? nwaves : 2048;   // persistent waves
        hipLaunchKernelGGL(agg_kernel, dim3(blocks), dim3(256), 0, stream,
                           Y16, rp, ci, out, n);
    } else {
        hipLaunchKernelGGL(gin_fused, dim3((n + 3) / 4), dim3(256), 0, stream,
                           X, W, rp, ci, out, n);
    }
}